// Round 3
// baseline (1222.621 us; speedup 1.0000x reference)
//
#include <hip/hip_runtime.h>
#include <math.h>

#define D      256
#define KCODES 1024
#define NROWS  65536
#define BETA   0.25f

#define MTILE 64
#define KTILE 64
#define DTILE 32
#define RPAD  68   // padded row dim for transposed LDS tiles (16B-aligned, breaks conflicts)

// ---------------- sum of squares per row, f64-accumulated, rounded to f32 ----------------
// One wave per row; lanes load float4, exact f64 products, shuffle reduce.
__global__ __launch_bounds__(256) void sumsq_kernel(const float* __restrict__ src,
                                                    float* __restrict__ dst) {
    int row  = blockIdx.x * 4 + (threadIdx.x >> 6);
    int lane = threadIdx.x & 63;
    float4 v = ((const float4*)(src + (size_t)row * D))[lane];
    double s = (double)v.x * v.x + (double)v.y * v.y +
               (double)v.z * v.z + (double)v.w * v.w;
    #pragma unroll
    for (int off = 32; off > 0; off >>= 1) s += __shfl_down(s, off, 64);
    if (lane == 0) dst[row] = (float)s;   // single correctly-rounded f32
}

// ---------------- argmin_k fl32( fl32(x2+e2) - 2*fl32(sim) ), sim in f64 ----------------
__global__ __launch_bounds__(256) void argmin_kernel(
    const float* __restrict__ x, const float* __restrict__ cb,
    const float* __restrict__ x2f, const float* __restrict__ e2f,
    float* __restrict__ out_idxf, unsigned int* __restrict__ counts)
{
    __shared__ float xT[DTILE][RPAD];   // d-major x tile    [d][row]
    __shared__ float cT[DTILE][RPAD];   // d-major code tile [d][code]
    __shared__ float rd[MTILE][16];
    __shared__ int   rk[MTILE][16];

    const int tid = threadIdx.x;
    const int tc  = tid & 15;           // code group 0..15
    const int tr  = tid >> 4;           // row group 0..15
    const int rowBase = blockIdx.x * MTILE;

    const int lr = tid >> 3;            // 0..31 (load row/code)
    const int lg = tid & 7;             // 0..7  (load d-group)

    float x2v[4];
    #pragma unroll
    for (int i = 0; i < 4; ++i) x2v[i] = x2f[rowBase + tr * 4 + i];

    float bestd[4] = {1e30f, 1e30f, 1e30f, 1e30f};
    int   bestk[4] = {0, 0, 0, 0};

    for (int kc = 0; kc < KCODES / KTILE; ++kc) {
        double acc[4][4];
        #pragma unroll
        for (int i = 0; i < 4; ++i)
            #pragma unroll
            for (int j = 0; j < 4; ++j) acc[i][j] = 0.0;

        for (int dc = 0; dc < D / DTILE; ++dc) {
            const int dofs = dc * DTILE + lg * 4;
            float4 xa = *(const float4*)&x [(size_t)(rowBase + lr)      * D + dofs];
            float4 xb = *(const float4*)&x [(size_t)(rowBase + lr + 32) * D + dofs];
            float4 ca = *(const float4*)&cb[(size_t)(kc * KTILE + lr)      * D + dofs];
            float4 cc = *(const float4*)&cb[(size_t)(kc * KTILE + lr + 32) * D + dofs];
            __syncthreads();            // prior iter's LDS reads complete
            const int db = lg * 4;
            xT[db + 0][lr]      = xa.x; xT[db + 1][lr]      = xa.y;
            xT[db + 2][lr]      = xa.z; xT[db + 3][lr]      = xa.w;
            xT[db + 0][lr + 32] = xb.x; xT[db + 1][lr + 32] = xb.y;
            xT[db + 2][lr + 32] = xb.z; xT[db + 3][lr + 32] = xb.w;
            cT[db + 0][lr]      = ca.x; cT[db + 1][lr]      = ca.y;
            cT[db + 2][lr]      = ca.z; cT[db + 3][lr]      = ca.w;
            cT[db + 0][lr + 32] = cc.x; cT[db + 1][lr + 32] = cc.y;
            cT[db + 2][lr + 32] = cc.z; cT[db + 3][lr + 32] = cc.w;
            __syncthreads();            // tiles visible

            #pragma unroll 4
            for (int dd = 0; dd < DTILE; ++dd) {
                float4 xf = *(const float4*)&xT[dd][tr * 4];
                float4 cf = *(const float4*)&cT[dd][tc * 4];
                double xd0 = xf.x, xd1 = xf.y, xd2 = xf.z, xd3 = xf.w;
                double cd0 = cf.x, cd1 = cf.y, cd2 = cf.z, cd3 = cf.w;
                acc[0][0] = fma(xd0, cd0, acc[0][0]);
                acc[0][1] = fma(xd0, cd1, acc[0][1]);
                acc[0][2] = fma(xd0, cd2, acc[0][2]);
                acc[0][3] = fma(xd0, cd3, acc[0][3]);
                acc[1][0] = fma(xd1, cd0, acc[1][0]);
                acc[1][1] = fma(xd1, cd1, acc[1][1]);
                acc[1][2] = fma(xd1, cd2, acc[1][2]);
                acc[1][3] = fma(xd1, cd3, acc[1][3]);
                acc[2][0] = fma(xd2, cd0, acc[2][0]);
                acc[2][1] = fma(xd2, cd1, acc[2][1]);
                acc[2][2] = fma(xd2, cd2, acc[2][2]);
                acc[2][3] = fma(xd2, cd3, acc[2][3]);
                acc[3][0] = fma(xd3, cd0, acc[3][0]);
                acc[3][1] = fma(xd3, cd1, acc[3][1]);
                acc[3][2] = fma(xd3, cd2, acc[3][2]);
                acc[3][3] = fma(xd3, cd3, acc[3][3]);
            }
        }

        // fp32 dist with the reference's quantization: fl(fl(x2+e2) - fl(2*sim))
        const int kb = kc * KTILE + tc * 4;
        float e20 = e2f[kb + 0], e21 = e2f[kb + 1];
        float e22 = e2f[kb + 2], e23 = e2f[kb + 3];
        #pragma unroll
        for (int i = 0; i < 4; ++i) {
            float s0 = (float)acc[i][0], s1 = (float)acc[i][1];
            float s2 = (float)acc[i][2], s3 = (float)acc[i][3];
            float t0 = x2v[i] + e20;
            float t1 = x2v[i] + e21;
            float t2 = x2v[i] + e22;
            float t3 = x2v[i] + e23;
            float d0 = t0 - 2.0f * s0;
            float d1 = t1 - 2.0f * s1;
            float d2 = t2 - 2.0f * s2;
            float d3 = t3 - 2.0f * s3;
            if (d0 < bestd[i]) { bestd[i] = d0; bestk[i] = kb + 0; }
            if (d1 < bestd[i]) { bestd[i] = d1; bestk[i] = kb + 1; }
            if (d2 < bestd[i]) { bestd[i] = d2; bestk[i] = kb + 2; }
            if (d3 < bestd[i]) { bestd[i] = d3; bestk[i] = kb + 3; }
        }
    }

    // cross-thread (same rows, 16 code-groups) reduction via LDS; ties -> lowest k
    #pragma unroll
    for (int i = 0; i < 4; ++i) {
        rd[tr * 4 + i][tc] = bestd[i];
        rk[tr * 4 + i][tc] = bestk[i];
    }
    __syncthreads();
    if (tid < MTILE) {
        float bd = rd[tid][0];
        int   bk = rk[tid][0];
        #pragma unroll
        for (int t = 1; t < 16; ++t) {
            float d = rd[tid][t];
            int   k = rk[tid][t];
            if (d < bd || (d == bd && k < bk)) { bd = d; bk = k; }
        }
        int row = rowBase + tid;
        out_idxf[row] = (float)bk;
        atomicAdd(&counts[bk], 1u);
    }
}

// ---------------- gather q, write y = x + (q - x), accumulate mse ----------------
__global__ __launch_bounds__(256) void gather_kernel(
    const float* __restrict__ x, const float* __restrict__ cb,
    const float* __restrict__ idxf, float* __restrict__ y,
    float* __restrict__ msesum)
{
    int t = blockIdx.x * 256 + threadIdx.x;   // float4 index
    int row = t >> 6;                         // 64 float4 per row
    int c4  = t & 63;
    int k = (int)idxf[row];                   // wave-uniform
    float4 q  = ((const float4*)cb)[(size_t)k * 64 + c4];
    float4 xv = ((const float4*)x)[t];
    float4 dv, yv;
    dv.x = q.x - xv.x; dv.y = q.y - xv.y; dv.z = q.z - xv.z; dv.w = q.w - xv.w;
    yv.x = xv.x + dv.x; yv.y = xv.y + dv.y; yv.z = xv.z + dv.z; yv.w = xv.w + dv.w;
    ((float4*)y)[t] = yv;

    float s = dv.x * dv.x + dv.y * dv.y + dv.z * dv.z + dv.w * dv.w;
    #pragma unroll
    for (int off = 32; off > 0; off >>= 1) s += __shfl_down(s, off, 64);
    __shared__ float ls[4];
    int lane = threadIdx.x & 63, w = threadIdx.x >> 6;
    if (lane == 0) ls[w] = s;
    __syncthreads();
    if (threadIdx.x == 0) atomicAdd(msesum, ls[0] + ls[1] + ls[2] + ls[3]);
}

// ---------------- final scalars: loss, perplexity, usage, H ----------------
__global__ __launch_bounds__(1024) void stats_kernel(
    const unsigned int* __restrict__ counts, const float* __restrict__ msesum,
    float* __restrict__ outs)
{
    int t = threadIdx.x;                      // 0..1023 -> one bin each
    float p = (float)counts[t] * (1.0f / 65536.0f);
    float h = -p * log2f(p + 1e-10f);
    float u = (p > 0.f) ? 1.f : 0.f;
    #pragma unroll
    for (int off = 32; off > 0; off >>= 1) {
        h += __shfl_down(h, off, 64);
        u += __shfl_down(u, off, 64);
    }
    __shared__ float hs[16], us[16];
    int lane = t & 63, w = t >> 6;
    if (lane == 0) { hs[w] = h; us[w] = u; }
    __syncthreads();
    if (t == 0) {
        float H = 0.f, U = 0.f;
        #pragma unroll
        for (int i = 0; i < 16; ++i) { H += hs[i]; U += us[i]; }
        float m = *msesum * (1.0f / 16777216.0f);
        float loss = BETA * m + m;
        float perp = expf(H * 0.69314718055994530942f);
        outs[0] = loss;
        outs[1] = perp;
        outs[2] = U * (1.0f / 1024.0f);
        outs[3] = H;
    }
}

extern "C" void kernel_launch(void* const* d_in, const int* in_sizes, int n_in,
                              void* d_out, int out_size, void* d_ws, size_t ws_size,
                              hipStream_t stream) {
    const float* x  = (const float*)d_in[0];   // [65536, 256]
    const float* cb = (const float*)d_in[1];   // [1024, 256]
    float* out      = (float*)d_out;

    float* y        = out;                      // 16,777,216
    float* out_idxf = out + 16777216;           // 65,536
    float* outs     = out + 16777216 + 65536;   // loss, perp, usage, H

    // ws layout (bytes):
    // [0        .. 262143] x2f (65536 f32)
    // [262144   .. 266239] e2f (1024 f32)
    // [266240   .. 270335] counts (1024 u32)
    // [270336   .. 270339] msesum (f32)
    float*        x2f    = (float*)d_ws;
    float*        e2f    = (float*)((char*)d_ws + 262144);
    unsigned int* counts = (unsigned int*)((char*)d_ws + 266240);
    float*        msesum = (float*)((char*)d_ws + 270336);

    hipMemsetAsync((char*)d_ws + 266240, 0, 4100, stream);  // counts + msesum
    sumsq_kernel<<<NROWS  / 4, 256, 0, stream>>>(x,  x2f);
    sumsq_kernel<<<KCODES / 4, 256, 0, stream>>>(cb, e2f);
    argmin_kernel<<<NROWS / MTILE, 256, 0, stream>>>(x, cb, x2f, e2f, out_idxf, counts);
    gather_kernel<<<(NROWS * D / 4) / 256, 256, 0, stream>>>(x, cb, out_idxf, y, msesum);
    stats_kernel<<<1, 1024, 0, stream>>>(counts, msesum, outs);
}

// Round 4
// 986.209 us; speedup vs baseline: 1.2397x; 1.2397x over previous
//
#include <hip/hip_runtime.h>
#include <math.h>

#define D      256
#define KCODES 1024
#define NROWS  65536
#define BETA   0.25f

#define MTILE 64
#define KTILE 64
#define DTILE 32
#define RPAD  68      // padded row dim for transposed LDS tiles
#define MARGIN 2e-4f  // quantization reorder bound (1.22e-4) + screening err + slack
#define MAXSURV 7

// ---------------- sum of squares per row, f64-accumulated, rounded to f32 ----------------
__global__ __launch_bounds__(256) void sumsq_kernel(const float* __restrict__ src,
                                                    float* __restrict__ dst) {
    int row  = blockIdx.x * 4 + (threadIdx.x >> 6);
    int lane = threadIdx.x & 63;
    float4 v = ((const float4*)(src + (size_t)row * D))[lane];
    double s = (double)v.x * v.x + (double)v.y * v.y +
               (double)v.z * v.z + (double)v.w * v.w;
    #pragma unroll
    for (int off = 32; off > 0; off >>= 1) s += __shfl_down(s, off, 64);
    if (lane == 0) dst[row] = (float)s;
}

// ---------------- fp32 screening: per-row survivors of argmin_k (e2[k] - 2 x.c_k) ----------------
__global__ __launch_bounds__(256) void screen_kernel(
    const float* __restrict__ x, const float* __restrict__ cb,
    const float* __restrict__ e2f, int* __restrict__ rowlist)
{
    __shared__ float xT[DTILE][RPAD];   // d-major x tile    [d][row]
    __shared__ float cT[DTILE][RPAD];   // d-major code tile [d][code]
    __shared__ float sd[MTILE][48];     // per-row candidate dists (16 threads x top-3)
    __shared__ int   sk[MTILE][48];

    const int tid = threadIdx.x;
    const int tc  = tid & 15;           // code group 0..15
    const int tr  = tid >> 4;           // row group 0..15
    const int rowBase = blockIdx.x * MTILE;

    const int lr = tid >> 3;            // 0..31 (load row/code)
    const int lg = tid & 7;             // 0..7  (load d-group)

    // per-row top-3 (b[i][0] <= b[i][1] <= b[i][2])
    float b1[4], b2[4], b3[4];
    int   q1[4], q2[4], q3[4];
    #pragma unroll
    for (int i = 0; i < 4; ++i) {
        b1[i] = 1e30f; b2[i] = 1e30f; b3[i] = 1e30f;
        q1[i] = 0;     q2[i] = 0;     q3[i] = 0;
    }

    for (int kc = 0; kc < KCODES / KTILE; ++kc) {
        float acc[4][4];
        #pragma unroll
        for (int i = 0; i < 4; ++i)
            #pragma unroll
            for (int j = 0; j < 4; ++j) acc[i][j] = 0.f;

        for (int dc = 0; dc < D / DTILE; ++dc) {
            const int dofs = dc * DTILE + lg * 4;
            float4 xa = *(const float4*)&x [(size_t)(rowBase + lr)      * D + dofs];
            float4 xb = *(const float4*)&x [(size_t)(rowBase + lr + 32) * D + dofs];
            float4 ca = *(const float4*)&cb[(size_t)(kc * KTILE + lr)      * D + dofs];
            float4 cc = *(const float4*)&cb[(size_t)(kc * KTILE + lr + 32) * D + dofs];
            __syncthreads();
            const int db = lg * 4;
            xT[db + 0][lr]      = xa.x; xT[db + 1][lr]      = xa.y;
            xT[db + 2][lr]      = xa.z; xT[db + 3][lr]      = xa.w;
            xT[db + 0][lr + 32] = xb.x; xT[db + 1][lr + 32] = xb.y;
            xT[db + 2][lr + 32] = xb.z; xT[db + 3][lr + 32] = xb.w;
            cT[db + 0][lr]      = ca.x; cT[db + 1][lr]      = ca.y;
            cT[db + 2][lr]      = ca.z; cT[db + 3][lr]      = ca.w;
            cT[db + 0][lr + 32] = cc.x; cT[db + 1][lr + 32] = cc.y;
            cT[db + 2][lr + 32] = cc.z; cT[db + 3][lr + 32] = cc.w;
            __syncthreads();

            #pragma unroll 8
            for (int dd = 0; dd < DTILE; ++dd) {
                float4 xf = *(const float4*)&xT[dd][tr * 4];
                float4 cf = *(const float4*)&cT[dd][tc * 4];
                acc[0][0] = fmaf(xf.x, cf.x, acc[0][0]);
                acc[0][1] = fmaf(xf.x, cf.y, acc[0][1]);
                acc[0][2] = fmaf(xf.x, cf.z, acc[0][2]);
                acc[0][3] = fmaf(xf.x, cf.w, acc[0][3]);
                acc[1][0] = fmaf(xf.y, cf.x, acc[1][0]);
                acc[1][1] = fmaf(xf.y, cf.y, acc[1][1]);
                acc[1][2] = fmaf(xf.y, cf.z, acc[1][2]);
                acc[1][3] = fmaf(xf.y, cf.w, acc[1][3]);
                acc[2][0] = fmaf(xf.z, cf.x, acc[2][0]);
                acc[2][1] = fmaf(xf.z, cf.y, acc[2][1]);
                acc[2][2] = fmaf(xf.z, cf.z, acc[2][2]);
                acc[2][3] = fmaf(xf.z, cf.w, acc[2][3]);
                acc[3][0] = fmaf(xf.w, cf.x, acc[3][0]);
                acc[3][1] = fmaf(xf.w, cf.y, acc[3][1]);
                acc[3][2] = fmaf(xf.w, cf.z, acc[3][2]);
                acc[3][3] = fmaf(xf.w, cf.w, acc[3][3]);
            }
        }

        const int kb = kc * KTILE + tc * 4;
        float e20 = e2f[kb + 0], e21 = e2f[kb + 1];
        float e22 = e2f[kb + 2], e23 = e2f[kb + 3];
        #pragma unroll
        for (int i = 0; i < 4; ++i) {
            float dv[4];
            dv[0] = e20 - 2.0f * acc[i][0];
            dv[1] = e21 - 2.0f * acc[i][1];
            dv[2] = e22 - 2.0f * acc[i][2];
            dv[3] = e23 - 2.0f * acc[i][3];
            #pragma unroll
            for (int j = 0; j < 4; ++j) {
                float d = dv[j];
                int   k = kb + j;
                if (d < b3[i]) {
                    if (d < b2[i]) {
                        b3[i] = b2[i]; q3[i] = q2[i];
                        if (d < b1[i]) { b2[i] = b1[i]; q2[i] = q1[i]; b1[i] = d; q1[i] = k; }
                        else           { b2[i] = d;     q2[i] = k; }
                    } else { b3[i] = d; q3[i] = k; }
                }
            }
        }
    }

    // dump per-thread top-3 into LDS, then per-row survivor selection
    #pragma unroll
    for (int i = 0; i < 4; ++i) {
        int row = tr * 4 + i;
        sd[row][tc * 3 + 0] = b1[i];  sk[row][tc * 3 + 0] = q1[i];
        sd[row][tc * 3 + 1] = b2[i];  sk[row][tc * 3 + 1] = q2[i];
        sd[row][tc * 3 + 2] = b3[i];  sk[row][tc * 3 + 2] = q3[i];
    }
    __syncthreads();
    if (tid < MTILE) {
        float dmin = 1e30f;
        #pragma unroll
        for (int t = 0; t < 48; ++t) dmin = fminf(dmin, sd[tid][t]);
        float lim = dmin + MARGIN;
        int* dst = rowlist + (size_t)(rowBase + tid) * 8;
        int cnt = 0;
        for (int t = 0; t < 48; ++t) {
            float d = sd[tid][t];
            if (d <= lim && cnt < MAXSURV) { dst[1 + cnt] = sk[tid][t]; ++cnt; }
        }
        dst[0] = cnt;
    }
}

// ---------------- exact rescore of survivors: one wave per row ----------------
__global__ __launch_bounds__(256) void rescore_kernel(
    const float* __restrict__ x, const float* __restrict__ cb,
    const float* __restrict__ x2f, const float* __restrict__ e2f,
    const int* __restrict__ rowlist, float* __restrict__ out_idxf,
    unsigned int* __restrict__ counts)
{
    int row  = blockIdx.x * 4 + (threadIdx.x >> 6);
    int lane = threadIdx.x & 63;
    const int* lst = rowlist + (size_t)row * 8;
    int cnt = lst[0];
    float x2 = x2f[row];
    float4 xv = ((const float4*)(x + (size_t)row * D))[lane];

    float bestd = 1e30f;
    int   bestk = 0x7fffffff;
    for (int s = 0; s < cnt; ++s) {
        int k = lst[1 + s];
        float4 cv = ((const float4*)(cb + (size_t)k * D))[lane];
        double p = (double)xv.x * cv.x + (double)xv.y * cv.y +
                   (double)xv.z * cv.z + (double)xv.w * cv.w;
        #pragma unroll
        for (int off = 32; off > 0; off >>= 1) p += __shfl_down(p, off, 64);
        // reference comparator (lane 0 has full sum)
        float simf = (float)p;                 // correctly-rounded f32 sim
        float t    = x2 + e2f[k];              // fl32(x2+e2)
        float dq   = t - 2.0f * simf;          // 2*simf exact; single f32 subtract
        if (dq < bestd || (dq == bestd && k < bestk)) { bestd = dq; bestk = k; }
    }
    if (lane == 0) {
        out_idxf[row] = (float)bestk;
        atomicAdd(&counts[bestk], 1u);
    }
}

// ---------------- gather q, write y = x + (q - x), accumulate mse ----------------
__global__ __launch_bounds__(256) void gather_kernel(
    const float* __restrict__ x, const float* __restrict__ cb,
    const float* __restrict__ idxf, float* __restrict__ y,
    float* __restrict__ msesum)
{
    int t = blockIdx.x * 256 + threadIdx.x;   // float4 index
    int row = t >> 6;
    int c4  = t & 63;
    int k = (int)idxf[row];
    float4 q  = ((const float4*)cb)[(size_t)k * 64 + c4];
    float4 xv = ((const float4*)x)[t];
    float4 dv, yv;
    dv.x = q.x - xv.x; dv.y = q.y - xv.y; dv.z = q.z - xv.z; dv.w = q.w - xv.w;
    yv.x = xv.x + dv.x; yv.y = xv.y + dv.y; yv.z = xv.z + dv.z; yv.w = xv.w + dv.w;
    ((float4*)y)[t] = yv;

    float s = dv.x * dv.x + dv.y * dv.y + dv.z * dv.z + dv.w * dv.w;
    #pragma unroll
    for (int off = 32; off > 0; off >>= 1) s += __shfl_down(s, off, 64);
    __shared__ float ls[4];
    int lane = threadIdx.x & 63, w = threadIdx.x >> 6;
    if (lane == 0) ls[w] = s;
    __syncthreads();
    if (threadIdx.x == 0) atomicAdd(msesum, ls[0] + ls[1] + ls[2] + ls[3]);
}

// ---------------- final scalars: loss, perplexity, usage, H ----------------
__global__ __launch_bounds__(1024) void stats_kernel(
    const unsigned int* __restrict__ counts, const float* __restrict__ msesum,
    float* __restrict__ outs)
{
    int t = threadIdx.x;
    float p = (float)counts[t] * (1.0f / 65536.0f);
    float h = -p * log2f(p + 1e-10f);
    float u = (p > 0.f) ? 1.f : 0.f;
    #pragma unroll
    for (int off = 32; off > 0; off >>= 1) {
        h += __shfl_down(h, off, 64);
        u += __shfl_down(u, off, 64);
    }
    __shared__ float hs[16], us[16];
    int lane = t & 63, w = t >> 6;
    if (lane == 0) { hs[w] = h; us[w] = u; }
    __syncthreads();
    if (t == 0) {
        float H = 0.f, U = 0.f;
        #pragma unroll
        for (int i = 0; i < 16; ++i) { H += hs[i]; U += us[i]; }
        float m = *msesum * (1.0f / 16777216.0f);
        float loss = BETA * m + m;
        float perp = expf(H * 0.69314718055994530942f);
        outs[0] = loss;
        outs[1] = perp;
        outs[2] = U * (1.0f / 1024.0f);
        outs[3] = H;
    }
}

extern "C" void kernel_launch(void* const* d_in, const int* in_sizes, int n_in,
                              void* d_out, int out_size, void* d_ws, size_t ws_size,
                              hipStream_t stream) {
    const float* x  = (const float*)d_in[0];   // [65536, 256]
    const float* cb = (const float*)d_in[1];   // [1024, 256]
    float* out      = (float*)d_out;

    float* y        = out;                      // 16,777,216
    float* out_idxf = out + 16777216;           // 65,536
    float* outs     = out + 16777216 + 65536;   // loss, perp, usage, H

    // ws layout (bytes):
    // [0       .. 262143] x2f (65536 f32)
    // [262144  .. 266239] e2f (1024 f32)
    // [266240  .. 270335] counts (1024 u32)
    // [270336  .. 270339] msesum (f32)
    // [270400  .. ~2.37M] rowlist (65536 rows x 8 ints)
    float*        x2f     = (float*)d_ws;
    float*        e2f     = (float*)((char*)d_ws + 262144);
    unsigned int* counts  = (unsigned int*)((char*)d_ws + 266240);
    float*        msesum  = (float*)((char*)d_ws + 270336);
    int*          rowlist = (int*)((char*)d_ws + 270400);

    hipMemsetAsync((char*)d_ws + 266240, 0, 4100, stream);  // counts + msesum
    sumsq_kernel<<<NROWS  / 4, 256, 0, stream>>>(x,  x2f);
    sumsq_kernel<<<KCODES / 4, 256, 0, stream>>>(cb, e2f);
    screen_kernel<<<NROWS / MTILE, 256, 0, stream>>>(x, cb, e2f, rowlist);
    rescore_kernel<<<NROWS / 4, 256, 0, stream>>>(x, cb, x2f, e2f, rowlist, out_idxf, counts);
    gather_kernel<<<(NROWS * D / 4) / 256, 256, 0, stream>>>(x, cb, out_idxf, y, msesum);
    stats_kernel<<<1, 1024, 0, stream>>>(counts, msesum, outs);
}